// Round 12
// baseline (1495.830 us; speedup 1.0000x reference)
//
#include <hip/hip_runtime.h>
#include <hip/hip_bf16.h>

#define B_   4
#define LQ_  4096
#define LS_  4096
#define DH_  1024
#define BQ_  64
#define BS_  256
#define NT_  (LS_/BS_)   /* 16 */
#define NTH  1024

typedef __bf16 bf16x8 __attribute__((ext_vector_type(8)));
typedef float  f32x4  __attribute__((ext_vector_type(4)));
typedef float  f32x16 __attribute__((ext_vector_type(16)));
typedef unsigned char u8;

#define WAITL()  asm volatile("s_waitcnt lgkmcnt(0)" ::: "memory")
#define BAR()    __builtin_amdgcn_s_barrier()

__device__ __forceinline__ unsigned short f2bf(float f) {
  union { __bf16 h; unsigned short u; } cv;
  cv.h = (__bf16)f;
  return cv.u;
}
__device__ __forceinline__ bf16x8 cvt8(f32x4 a, f32x4 b) {
  bf16x8 r;
  r[0] = (__bf16)a[0]; r[1] = (__bf16)a[1]; r[2] = (__bf16)a[2]; r[3] = (__bf16)a[3];
  r[4] = (__bf16)b[0]; r[5] = (__bf16)b[1]; r[6] = (__bf16)b[2]; r[7] = (__bf16)b[3];
  return r;
}

// ---- fp32 S -> fragment-major bf16 layouts (wave-contiguous 1KB ring loads) ----
// (unchanged from r11; layouts serve both 8-wave and 16-wave consumers)
__global__ __launch_bounds__(256) void cvt_kernel(const float* __restrict__ S,
                                                  u8* __restrict__ Kf,
                                                  u8* __restrict__ Vf)
{
  __shared__ unsigned short tile[64][72];
  const int b  = blockIdx.z;
  const int dt = blockIdx.y;   // 0..15  (64 d each)
  const int st = blockIdx.x;   // 0..63  (64 s each)
  const int tid = threadIdx.x;
  const int t  = st >> 2;
  const float* Sbase = S + ((size_t)b*LS_ + (size_t)st*64)*DH_ + dt*64;

  #pragma unroll
  for (int k = 0; k < 4; ++k) {
    int fi  = tid + k*256;
    int row = fi >> 4;
    int c4  = fi & 15;
    float4 v = *reinterpret_cast<const float4*>(Sbase + (size_t)row*DH_ + c4*4);
    ushort4 h;
    h.x = f2bf(v.x); h.y = f2bf(v.y); h.z = f2bf(v.z); h.w = f2bf(v.w);
    *reinterpret_cast<ushort4*>(&tile[row][c4*4]) = h;
  }
  __syncthreads();

  // Kf: 8x 1KB blocks
  #pragma unroll
  for (int h2 = 0; h2 < 2; ++h2) {
    int u    = tid + h2*256;
    int blk  = u >> 6;
    int wloc = blk >> 2;
    int kkl  = blk & 3;
    int lane = u & 63;
    int sh   = lane >> 5, sl = lane & 31;
    int srow = wloc*32 + sl;
    int scol = kkl*16 + sh*8;
    ushort4 h0 = *reinterpret_cast<const ushort4*>(&tile[srow][scol]);
    ushort4 h1 = *reinterpret_cast<const ushort4*>(&tile[srow][scol+4]);
    int w_g  = (st & 3)*2 + wloc;
    int kk_g = dt*4 + kkl;
    u8* dst = Kf + (size_t)(((b*16 + t)*8 + w_g)*64 + kk_g)*1024 + lane*16;
    *reinterpret_cast<ushort4*>(dst)     = h0;
    *reinterpret_cast<ushort4*>(dst + 8) = h1;
  }

  // Vf: 8x 1KB blocks (transposed gather)
  #pragma unroll
  for (int h2 = 0; h2 < 2; ++h2) {
    int u    = tid + h2*256;
    int blk  = u >> 6;
    int ksl  = blk >> 2;
    int nfl  = blk & 3;
    int lane = u & 63;
    int lg   = lane >> 4, lr = lane & 15;
    int srow = ksl*32 + lg*8;
    int dcol = nfl*16 + lr;
    ushort4 h0, h1;
    h0.x = tile[srow+0][dcol]; h0.y = tile[srow+1][dcol];
    h0.z = tile[srow+2][dcol]; h0.w = tile[srow+3][dcol];
    h1.x = tile[srow+4][dcol]; h1.y = tile[srow+5][dcol];
    h1.z = tile[srow+6][dcol]; h1.w = tile[srow+7][dcol];
    int w_g = dt >> 1;
    int i_g = ((st & 3)*2 + ksl)*8 + (dt & 1)*4 + nfl;
    u8* dst = Vf + (size_t)(((b*16 + t)*8 + w_g)*64 + i_g)*1024 + lane*16;
    *reinterpret_cast<ushort4*>(dst)     = h0;
    *reinterpret_cast<ushort4*>(dst + 8) = h1;
  }
}

// ---------------- fused flash attention, 16 waves (4/SIMD), m==0 softmax ----------------
// Wave (qh=w&1, ws=w>>1): QK^T C[qh's 32q][ws's 32s] via 32x32x16.
// PV: wave owns d in [w*64, w*64+64): Oacc[4 mq][4 nf] via 16x16x32.
// Fused QK(t) + PV(t-1); rings distance 4; 2 barriers/tile.
__global__ __launch_bounds__(NTH, 1) void attn_kernel(
    const float* __restrict__ Qg,
    const u8* __restrict__ Kf,
    const u8* __restrict__ Vf,
    float* __restrict__ Og)
{
  __shared__ __align__(16) unsigned char qlds[131072];  // [qf:2][kk:64][lane:64]*16B
  __shared__ __align__(16) unsigned char plds[32768];   // P [64 q][256 s] bf16 swizzled

  const int tid = threadIdx.x;
  const int w  = tid >> 6;        // 0..15
  const int l  = tid & 63;
  const int lg = l >> 4;
  const int lr = l & 15;
  const int sl = l & 31;
  const int sh = l >> 5;
  const int qh = w & 1;           // Q half (QK) and V nf-group
  const int ws = w >> 1;          // s-slice (QK), w8 group (V/K)

  const int n    = blockIdx.x;
  const int xcd  = n & 7;
  const int slot = n >> 3;
  const int b    = xcd >> 1;
  const int qt   = (xcd & 1)*32 + slot;

  const float* Qbase = Qg + ((size_t)b*LQ_ + (size_t)qt*BQ_)*DH_;
  const u8* kptr = Kf + (size_t)b*8388608 + (size_t)ws*65536 + l*16;
  const u8* vptr = Vf + (size_t)b*8388608 + (size_t)ws*65536 + l*16;
  const int voff = qh*4;          // V unit offset within ks-group

  bf16x8 bk[4], bv[4];
  auto ldU = [&](const u8* base, int unit) -> bf16x8 {
    return *reinterpret_cast<const bf16x8*>(base + unit*1024);
  };
  auto ldP = [&](int mq, int ks) -> bf16x8 {
    int q = mq*16 + lr;
    return *reinterpret_cast<const bf16x8*>(
        plds + q*512 + ((ks*64 + lg*16) ^ ((q & 7) << 4)));
  };
  auto ldA = [&](int kk) -> bf16x8 {
    return *reinterpret_cast<const bf16x8*>(qlds + qh*65536 + kk*1024 + l*16);
  };

  // K-ring fill for t=0 (in flight across Q staging)
  bk[0] = ldU(kptr, 0); bk[1] = ldU(kptr, 1);
  bk[2] = ldU(kptr, 2); bk[3] = ldU(kptr, 3);

  // ---- stage Q fp32 -> bf16 into lane-linear fragment layout (once) ----
  #pragma unroll
  for (int it = 0; it < 8; ++it) {
    int u  = tid + it*NTH;          // 0..8191 units of 16 B
    int qf = u >> 12;
    int kk = (u >> 6) & 63;
    int ll = u & 63;
    int q  = qf*32 + (ll & 31);
    int d  = kk*16 + (ll >> 5)*8;
    const float* p = Qbase + (size_t)q*DH_ + d;
    f32x4 v0 = *reinterpret_cast<const f32x4*>(p);
    f32x4 v1 = *reinterpret_cast<const f32x4*>(p + 4);
    *reinterpret_cast<bf16x8*>(qlds + (size_t)u*16) = cvt8(v0, v1);
  }

  f32x4 Oacc[4][4];
  #pragma unroll
  for (int i = 0; i < 4; ++i)
    #pragma unroll
    for (int j = 0; j < 4; ++j)
      Oacc[i][j] = (f32x4){0.f, 0.f, 0.f, 0.f};
  f32x4 lacc[4];
  #pragma unroll
  for (int i = 0; i < 4; ++i) lacc[i] = (f32x4){0.f, 0.f, 0.f, 0.f};

  bf16x8 ones;
  #pragma unroll
  for (int e = 0; e < 8; ++e) ones[e] = (__bf16)1.0f;

  f32x16 qk;
  const float SCL = 0.04508422f;   // (1/32) * log2(e)

  WAITL();
  BAR();   // Q staged (K-ring loads stay in flight)

  // ================= QK-only prologue: tile 0 =================
  #pragma unroll
  for (int r = 0; r < 16; ++r) qk[r] = 0.f;
  {
    bf16x8 aqA = ldA(0);
    #pragma unroll 1
    for (int ib = 0; ib < 7; ++ib) {
      #pragma unroll
      for (int j2 = 0; j2 < 8; ++j2) {
        const int kk = ib*8 + j2;
        bf16x8 aqN = ldA(kk + 1);
        __builtin_amdgcn_s_setprio(1);
        qk = __builtin_amdgcn_mfma_f32_32x32x16_bf16(aqA, bk[j2 & 3], qk, 0, 0, 0);
        __builtin_amdgcn_s_setprio(0);
        bk[j2 & 3] = ldU(kptr, kk + 4);
        aqA = aqN;
      }
    }
    #pragma unroll
    for (int j2 = 0; j2 < 8; ++j2) {                   // tail j = 56..63
      const int j = 56 + j2;
      bf16x8 aqN = (j < 63) ? ldA(j + 1) : aqA;
      __builtin_amdgcn_s_setprio(1);
      qk = __builtin_amdgcn_mfma_f32_32x32x16_bf16(aqA, bk[j2 & 3], qk, 0, 0, 0);
      __builtin_amdgcn_s_setprio(0);
      if (j2 < 4) bk[j2] = ldU(kptr, 60 + j2);
      else {
        bk[j2 - 4] = ldU(kptr + 524288, j2 - 4);       // K(1) units 0..3
        bv[j2 - 4] = ldU(vptr, voff + (j2 - 4));       // V(0) ks=0
      }
      aqA = aqN;
    }
  }

  // ================= main: t = 1..15, fused QK(t) + PV(t-1) =================
  #pragma unroll 1
  for (int t = 1; t < NT_; ++t) {
    BAR();   // all waves' plds reads of P(t-2) done

    // softmax(t-1): P = exp2(scl*logit) -> plds
    #pragma unroll
    for (int r = 0; r < 16; ++r) {
      int q = qh*32 + (r & 3) + 8*(r >> 2) + 4*sh;
      int s = ws*32 + sl;
      float p = exp2f(qk[r] * SCL);
      *reinterpret_cast<__bf16*>(plds + q*512 + ((s*2) ^ ((q & 7) << 4))) = (__bf16)p;
    }
    WAITL();
    BAR();   // P(t-1) visible

    #pragma unroll
    for (int r = 0; r < 16; ++r) qk[r] = 0.f;

    const u8* kT = kptr + (size_t)t*524288;
    const u8* vT = vptr + (size_t)(t-1)*524288;
    bf16x8 aqA = ldA(0);
    bf16x8 pa0, pa1, pa2, pa3;

    #pragma unroll 1
    for (int ib = 0; ib < 7; ++ib) {
      #pragma unroll
      for (int j2 = 0; j2 < 8; ++j2) {
        const int j = ib*8 + j2;
        bf16x8 aqN = ldA(j + 1);
        if (j2 == 0) {
          pa0 = ldP(0, ib); pa1 = ldP(1, ib); pa2 = ldP(2, ib); pa3 = ldP(3, ib);
          if (qh == 0 && ws == ib) {
            lacc[0] = __builtin_amdgcn_mfma_f32_16x16x32_bf16(pa0, ones, lacc[0], 0, 0, 0);
            lacc[1] = __builtin_amdgcn_mfma_f32_16x16x32_bf16(pa1, ones, lacc[1], 0, 0, 0);
            lacc[2] = __builtin_amdgcn_mfma_f32_16x16x32_bf16(pa2, ones, lacc[2], 0, 0, 0);
            lacc[3] = __builtin_amdgcn_mfma_f32_16x16x32_bf16(pa3, ones, lacc[3], 0, 0, 0);
          }
        }
        const int nf = j2 >> 1;
        __builtin_amdgcn_s_setprio(1);
        qk = __builtin_amdgcn_mfma_f32_32x32x16_bf16(aqA, bk[j2 & 3], qk, 0, 0, 0);
        if ((j2 & 1) == 0) {
          Oacc[0][nf] = __builtin_amdgcn_mfma_f32_16x16x32_bf16(pa0, bv[nf], Oacc[0][nf], 0, 0, 0);
          Oacc[1][nf] = __builtin_amdgcn_mfma_f32_16x16x32_bf16(pa1, bv[nf], Oacc[1][nf], 0, 0, 0);
        } else {
          Oacc[2][nf] = __builtin_amdgcn_mfma_f32_16x16x32_bf16(pa2, bv[nf], Oacc[2][nf], 0, 0, 0);
          Oacc[3][nf] = __builtin_amdgcn_mfma_f32_16x16x32_bf16(pa3, bv[nf], Oacc[3][nf], 0, 0, 0);
        }
        __builtin_amdgcn_s_setprio(0);
        bk[j2 & 3] = ldU(kT, j + 4);
        if (j2 & 1) bv[nf] = ldU(vT, (ib + 1)*8 + voff + nf);
        aqA = aqN;
      }
    }
    #pragma unroll
    for (int j2 = 0; j2 < 8; ++j2) {                   // tail ib=7, j = 56..63
      const int j = 56 + j2;
      bf16x8 aqN = (j < 63) ? ldA(j + 1) : aqA;
      if (j2 == 0) {
        pa0 = ldP(0, 7); pa1 = ldP(1, 7); pa2 = ldP(2, 7); pa3 = ldP(3, 7);
        if (qh == 0 && ws == 7) {
          lacc[0] = __builtin_amdgcn_mfma_f32_16x16x32_bf16(pa0, ones, lacc[0], 0, 0, 0);
          lacc[1] = __builtin_amdgcn_mfma_f32_16x16x32_bf16(pa1, ones, lacc[1], 0, 0, 0);
          lacc[2] = __builtin_amdgcn_mfma_f32_16x16x32_bf16(pa2, ones, lacc[2], 0, 0, 0);
          lacc[3] = __builtin_amdgcn_mfma_f32_16x16x32_bf16(pa3, ones, lacc[3], 0, 0, 0);
        }
      }
      const int nf = j2 >> 1;
      __builtin_amdgcn_s_setprio(1);
      qk = __builtin_amdgcn_mfma_f32_32x32x16_bf16(aqA, bk[j2 & 3], qk, 0, 0, 0);
      if ((j2 & 1) == 0) {
        Oacc[0][nf] = __builtin_amdgcn_mfma_f32_16x16x32_bf16(pa0, bv[nf], Oacc[0][nf], 0, 0, 0);
        Oacc[1][nf] = __builtin_amdgcn_mfma_f32_16x16x32_bf16(pa1, bv[nf], Oacc[1][nf], 0, 0, 0);
      } else {
        Oacc[2][nf] = __builtin_amdgcn_mfma_f32_16x16x32_bf16(pa2, bv[nf], Oacc[2][nf], 0, 0, 0);
        Oacc[3][nf] = __builtin_amdgcn_mfma_f32_16x16x32_bf16(pa3, bv[nf], Oacc[3][nf], 0, 0, 0);
      }
      __builtin_amdgcn_s_setprio(0);
      if (j2 < 4) bk[j2] = ldU(kT, 60 + j2);
      else        bk[j2 - 4] = ldU(kT + 524288, j2 - 4);   // K(t+1)
      if (j2 & 1) bv[nf] = ldU(vT + 524288, voff + nf);    // V(t) ks=0
      aqA = aqN;
    }
  }

  // ================= epilogue: softmax(15) + PV-only =================
  BAR();
  #pragma unroll
  for (int r = 0; r < 16; ++r) {
    int q = qh*32 + (r & 3) + 8*(r >> 2) + 4*sh;
    int s = ws*32 + sl;
    float p = exp2f(qk[r] * SCL);
    *reinterpret_cast<__bf16*>(plds + q*512 + ((s*2) ^ ((q & 7) << 4))) = (__bf16)p;
  }
  WAITL();
  BAR();

  {
    const u8* vT = vptr + (size_t)(NT_-1)*524288;
    bf16x8 pa0, pa1, pa2, pa3;
    #pragma unroll 1
    for (int ib = 0; ib < 8; ++ib) {
      #pragma unroll
      for (int j2 = 0; j2 < 8; ++j2) {
        if (j2 == 0) {
          pa0 = ldP(0, ib); pa1 = ldP(1, ib); pa2 = ldP(2, ib); pa3 = ldP(3, ib);
          if (qh == 0 && ws == ib) {
            lacc[0] = __builtin_amdgcn_mfma_f32_16x16x32_bf16(pa0, ones, lacc[0], 0, 0, 0);
            lacc[1] = __builtin_amdgcn_mfma_f32_16x16x32_bf16(pa1, ones, lacc[1], 0, 0, 0);
            lacc[2] = __builtin_amdgcn_mfma_f32_16x16x32_bf16(pa2, ones, lacc[2], 0, 0, 0);
            lacc[3] = __builtin_amdgcn_mfma_f32_16x16x32_bf16(pa3, ones, lacc[3], 0, 0, 0);
          }
        }
        const int nf = j2 >> 1;
        __builtin_amdgcn_s_setprio(1);
        if ((j2 & 1) == 0) {
          Oacc[0][nf] = __builtin_amdgcn_mfma_f32_16x16x32_bf16(pa0, bv[nf], Oacc[0][nf], 0, 0, 0);
          Oacc[1][nf] = __builtin_amdgcn_mfma_f32_16x16x32_bf16(pa1, bv[nf], Oacc[1][nf], 0, 0, 0);
        } else {
          Oacc[2][nf] = __builtin_amdgcn_mfma_f32_16x16x32_bf16(pa2, bv[nf], Oacc[2][nf], 0, 0, 0);
          Oacc[3][nf] = __builtin_amdgcn_mfma_f32_16x16x32_bf16(pa3, bv[nf], Oacc[3][nf], 0, 0, 0);
        }
        __builtin_amdgcn_s_setprio(0);
        if ((j2 & 1) && ib < 7) bv[nf] = ldU(vT, (ib + 1)*8 + voff + nf);
      }
    }
  }
  BAR();   // all plds reads done

  // ================= l: combine 8 ks-partials, write O =================
  float* lred = (float*)plds;
  if (qh == 0 && lr == 0) {
    #pragma unroll
    for (int mq = 0; mq < 4; ++mq)
      #pragma unroll
      for (int j = 0; j < 4; ++j)
        lred[ws*64 + mq*16 + lg*4 + j] = lacc[mq][j];
  }
  WAITL();
  BAR();

  float* Ob = Og + ((size_t)b*LQ_ + (size_t)qt*BQ_)*DH_;
  #pragma unroll
  for (int mq = 0; mq < 4; ++mq)
    #pragma unroll
    for (int j = 0; j < 4; ++j) {
      int q = mq*16 + lg*4 + j;
      float s = 0.f;
      #pragma unroll
      for (int k = 0; k < 8; ++k) s += lred[k*64 + q];
      float rinv = 1.0f / s;
      #pragma unroll
      for (int nf = 0; nf < 4; ++nf)
        Ob[(size_t)q*DH_ + w*64 + nf*16 + lr] = Oacc[mq][nf][j] * rinv;
    }
}

// ---------------- correctness-only fallback (ws too small; never expected) ----------------
__global__ void attn_naive(const float* __restrict__ Q, const float* __restrict__ S,
                           float* __restrict__ O)
{
  const int row = blockIdx.x;
  const int b = row >> 12, q = row & 4095;
  const float* qp = Q + ((size_t)b*LQ_ + q)*DH_;
  const float* sp = S + (size_t)b*LS_*DH_;
  __shared__ float qs[DH_];
  __shared__ float osum[DH_];
  __shared__ float lsum;
  for (int i = threadIdx.x; i < DH_; i += 256) { qs[i] = qp[i]; osum[i] = 0.f; }
  if (threadIdx.x == 0) lsum = 0.f;
  __syncthreads();
  float lpart = 0.f;
  for (int s0 = threadIdx.x; s0 < LS_; s0 += 256) {
    const float* sr = sp + (size_t)s0*DH_;
    float dot = 0.f;
    for (int d = 0; d < DH_; ++d) dot += qs[d]*sr[d];
    float p = __expf(dot * 0.03125f);
    lpart += p;
    for (int d = 0; d < DH_; ++d) atomicAdd(&osum[d], p*sr[d]);
  }
  atomicAdd(&lsum, lpart);
  __syncthreads();
  float rinv = 1.0f / lsum;
  float* op = O + ((size_t)b*LQ_ + q)*DH_;
  for (int i = threadIdx.x; i < DH_; i += 256) op[i] = osum[i]*rinv;
}

extern "C" void kernel_launch(void* const* d_in, const int* in_sizes, int n_in,
                              void* d_out, int out_size, void* d_ws, size_t ws_size,
                              hipStream_t stream)
{
  const float* Q = (const float*)d_in[0];
  const float* S = (const float*)d_in[1];
  float* out = (float*)d_out;

  const size_t kf_bytes = (size_t)B_*NT_*8*64*1024;   // 32 MiB (bf16)
  const size_t vf_bytes = (size_t)B_*NT_*8*64*1024;   // 32 MiB (bf16)
  const size_t need = kf_bytes + vf_bytes;            // 64 MiB

  if (ws_size >= need) {
    u8* Kf = (u8*)d_ws;
    u8* Vf = Kf + kf_bytes;
    cvt_kernel<<<dim3(64, 16, 4), 256, 0, stream>>>(S, Kf, Vf);
    attn_kernel<<<dim3(256), NTH, 0, stream>>>(Q, Kf, Vf, out);
  } else {
    attn_naive<<<dim3(B_*LQ_), 256, 0, stream>>>(Q, S, out);
  }
}

// Round 13
// 1486.154 us; speedup vs baseline: 1.0065x; 1.0065x over previous
//
#include <hip/hip_runtime.h>
#include <hip/hip_bf16.h>

#define B_   4
#define LQ_  4096
#define LS_  4096
#define DH_  1024
#define BQ_  64
#define BS_  256
#define NT_  (LS_/BS_)   /* 16 */
#define NTH  1024

typedef __bf16 bf16x8 __attribute__((ext_vector_type(8)));
typedef float  f32x4  __attribute__((ext_vector_type(4)));
typedef float  f32x16 __attribute__((ext_vector_type(16)));
typedef unsigned char u8;

#define WAITL()  asm volatile("s_waitcnt lgkmcnt(0)" ::: "memory")
#define BAR()    __builtin_amdgcn_s_barrier()

__device__ __forceinline__ unsigned short f2bf(float f) {
  union { __bf16 h; unsigned short u; } cv;
  cv.h = (__bf16)f;
  return cv.u;
}
__device__ __forceinline__ bf16x8 cvt8(f32x4 a, f32x4 b) {
  bf16x8 r;
  r[0] = (__bf16)a[0]; r[1] = (__bf16)a[1]; r[2] = (__bf16)a[2]; r[3] = (__bf16)a[3];
  r[4] = (__bf16)b[0]; r[5] = (__bf16)b[1]; r[6] = (__bf16)b[2]; r[7] = (__bf16)b[3];
  return r;
}

// ---- fp32 S -> fragment-major bf16 layouts (wave-contiguous 1KB ring loads) ----
__global__ __launch_bounds__(256) void cvt_kernel(const float* __restrict__ S,
                                                  u8* __restrict__ Kf,
                                                  u8* __restrict__ Vf)
{
  __shared__ unsigned short tile[64][72];
  const int b  = blockIdx.z;
  const int dt = blockIdx.y;   // 0..15  (64 d each)
  const int st = blockIdx.x;   // 0..63  (64 s each)
  const int tid = threadIdx.x;
  const int t  = st >> 2;
  const float* Sbase = S + ((size_t)b*LS_ + (size_t)st*64)*DH_ + dt*64;

  #pragma unroll
  for (int k = 0; k < 4; ++k) {
    int fi  = tid + k*256;
    int row = fi >> 4;
    int c4  = fi & 15;
    float4 v = *reinterpret_cast<const float4*>(Sbase + (size_t)row*DH_ + c4*4);
    ushort4 h;
    h.x = f2bf(v.x); h.y = f2bf(v.y); h.z = f2bf(v.z); h.w = f2bf(v.w);
    *reinterpret_cast<ushort4*>(&tile[row][c4*4]) = h;
  }
  __syncthreads();

  // Kf: 8x 1KB blocks
  #pragma unroll
  for (int h2 = 0; h2 < 2; ++h2) {
    int u    = tid + h2*256;
    int blk  = u >> 6;
    int wloc = blk >> 2;
    int kkl  = blk & 3;
    int lane = u & 63;
    int sh   = lane >> 5, sl = lane & 31;
    int srow = wloc*32 + sl;
    int scol = kkl*16 + sh*8;
    ushort4 h0 = *reinterpret_cast<const ushort4*>(&tile[srow][scol]);
    ushort4 h1 = *reinterpret_cast<const ushort4*>(&tile[srow][scol+4]);
    int w_g  = (st & 3)*2 + wloc;
    int kk_g = dt*4 + kkl;
    u8* dst = Kf + (size_t)(((b*16 + t)*8 + w_g)*64 + kk_g)*1024 + lane*16;
    *reinterpret_cast<ushort4*>(dst)     = h0;
    *reinterpret_cast<ushort4*>(dst + 8) = h1;
  }

  // Vf: 8x 1KB blocks (transposed gather)
  #pragma unroll
  for (int h2 = 0; h2 < 2; ++h2) {
    int u    = tid + h2*256;
    int blk  = u >> 6;
    int ksl  = blk >> 2;
    int nfl  = blk & 3;
    int lane = u & 63;
    int lg   = lane >> 4, lr = lane & 15;
    int srow = ksl*32 + lg*8;
    int dcol = nfl*16 + lr;
    ushort4 h0, h1;
    h0.x = tile[srow+0][dcol]; h0.y = tile[srow+1][dcol];
    h0.z = tile[srow+2][dcol]; h0.w = tile[srow+3][dcol];
    h1.x = tile[srow+4][dcol]; h1.y = tile[srow+5][dcol];
    h1.z = tile[srow+6][dcol]; h1.w = tile[srow+7][dcol];
    int w_g = dt >> 1;
    int i_g = ((st & 3)*2 + ksl)*8 + (dt & 1)*4 + nfl;
    u8* dst = Vf + (size_t)(((b*16 + t)*8 + w_g)*64 + i_g)*1024 + lane*16;
    *reinterpret_cast<ushort4*>(dst)     = h0;
    *reinterpret_cast<ushort4*>(dst + 8) = h1;
  }
}

// ---------------- fused flash attention, 16 waves (4/SIMD), m==0 softmax ----------------
// Wave (qh=w&1, ws=w>>1): QK^T C[qh's 32q][ws's 32s] via 32x32x16.
// PV: wave owns d in [w*64, w*64+64): Oacc[4 mq][4 nf] via 16x16x32.
// __launch_bounds__(1024,4): target exactly 4 waves/EU -> 128 arch-VGPR cap
// (r12's (1024,1) let the allocator target 8 waves/EU = 64 regs -> total spill).
__global__ __launch_bounds__(NTH, 4) void attn_kernel(
    const float* __restrict__ Qg,
    const u8* __restrict__ Kf,
    const u8* __restrict__ Vf,
    float* __restrict__ Og)
{
  __shared__ __align__(16) unsigned char qlds[131072];  // [qf:2][kk:64][lane:64]*16B
  __shared__ __align__(16) unsigned char plds[32768];   // P [64 q][256 s] bf16 swizzled

  const int tid = threadIdx.x;
  const int w  = tid >> 6;        // 0..15
  const int l  = tid & 63;
  const int lg = l >> 4;
  const int lr = l & 15;
  const int sl = l & 31;
  const int sh = l >> 5;
  const int qh = w & 1;           // Q half (QK) and V nf-group
  const int ws = w >> 1;          // s-slice (QK), w8 group (V/K)

  const int n    = blockIdx.x;
  const int xcd  = n & 7;
  const int slot = n >> 3;
  const int b    = xcd >> 1;
  const int qt   = (xcd & 1)*32 + slot;

  const float* Qbase = Qg + ((size_t)b*LQ_ + (size_t)qt*BQ_)*DH_;
  const u8* kptr = Kf + (size_t)b*8388608 + (size_t)ws*65536 + l*16;
  const u8* vptr = Vf + (size_t)b*8388608 + (size_t)ws*65536 + l*16;
  const int voff = qh*4;          // V unit offset within ks-group

  bf16x8 bk[4], bv[4];
  auto ldU = [&](const u8* base, int unit) -> bf16x8 {
    return *reinterpret_cast<const bf16x8*>(base + unit*1024);
  };
  auto ldP = [&](int mq, int ks) -> bf16x8 {
    int q = mq*16 + lr;
    return *reinterpret_cast<const bf16x8*>(
        plds + q*512 + ((ks*64 + lg*16) ^ ((q & 7) << 4)));
  };
  auto ldA = [&](int kk) -> bf16x8 {
    return *reinterpret_cast<const bf16x8*>(qlds + qh*65536 + kk*1024 + l*16);
  };

  // K-ring fill for t=0 (in flight across Q staging)
  bk[0] = ldU(kptr, 0); bk[1] = ldU(kptr, 1);
  bk[2] = ldU(kptr, 2); bk[3] = ldU(kptr, 3);

  // ---- stage Q fp32 -> bf16 into lane-linear fragment layout (once) ----
  #pragma unroll
  for (int it = 0; it < 8; ++it) {
    int u  = tid + it*NTH;          // 0..8191 units of 16 B
    int qf = u >> 12;
    int kk = (u >> 6) & 63;
    int ll = u & 63;
    int q  = qf*32 + (ll & 31);
    int d  = kk*16 + (ll >> 5)*8;
    const float* p = Qbase + (size_t)q*DH_ + d;
    f32x4 v0 = *reinterpret_cast<const f32x4*>(p);
    f32x4 v1 = *reinterpret_cast<const f32x4*>(p + 4);
    *reinterpret_cast<bf16x8*>(qlds + (size_t)u*16) = cvt8(v0, v1);
  }

  f32x4 Oacc[4][4];
  #pragma unroll
  for (int i = 0; i < 4; ++i)
    #pragma unroll
    for (int j = 0; j < 4; ++j)
      Oacc[i][j] = (f32x4){0.f, 0.f, 0.f, 0.f};
  f32x4 lacc[4];
  #pragma unroll
  for (int i = 0; i < 4; ++i) lacc[i] = (f32x4){0.f, 0.f, 0.f, 0.f};

  bf16x8 ones;
  #pragma unroll
  for (int e = 0; e < 8; ++e) ones[e] = (__bf16)1.0f;

  f32x16 qk;
  const float SCL = 0.04508422f;   // (1/32) * log2(e)

  WAITL();
  BAR();   // Q staged (K-ring loads stay in flight)

  // ================= QK-only prologue: tile 0 =================
  #pragma unroll
  for (int r = 0; r < 16; ++r) qk[r] = 0.f;
  {
    bf16x8 aqA = ldA(0);
    #pragma unroll 1
    for (int ib = 0; ib < 7; ++ib) {
      #pragma unroll
      for (int j2 = 0; j2 < 8; ++j2) {
        const int kk = ib*8 + j2;
        bf16x8 aqN = ldA(kk + 1);
        __builtin_amdgcn_s_setprio(1);
        qk = __builtin_amdgcn_mfma_f32_32x32x16_bf16(aqA, bk[j2 & 3], qk, 0, 0, 0);
        __builtin_amdgcn_s_setprio(0);
        bk[j2 & 3] = ldU(kptr, kk + 4);
        aqA = aqN;
      }
    }
    #pragma unroll
    for (int j2 = 0; j2 < 8; ++j2) {                   // tail j = 56..63
      const int j = 56 + j2;
      bf16x8 aqN = (j < 63) ? ldA(j + 1) : aqA;
      __builtin_amdgcn_s_setprio(1);
      qk = __builtin_amdgcn_mfma_f32_32x32x16_bf16(aqA, bk[j2 & 3], qk, 0, 0, 0);
      __builtin_amdgcn_s_setprio(0);
      if (j2 < 4) bk[j2] = ldU(kptr, 60 + j2);
      else {
        bk[j2 - 4] = ldU(kptr + 524288, j2 - 4);       // K(1) units 0..3
        bv[j2 - 4] = ldU(vptr, voff + (j2 - 4));       // V(0) ks=0
      }
      aqA = aqN;
    }
  }

  // ================= main: t = 1..15, fused QK(t) + PV(t-1) =================
  #pragma unroll 1
  for (int t = 1; t < NT_; ++t) {
    BAR();   // all waves' plds reads of P(t-2) done

    // softmax(t-1): P = exp2(scl*logit) -> plds
    #pragma unroll
    for (int r = 0; r < 16; ++r) {
      int q = qh*32 + (r & 3) + 8*(r >> 2) + 4*sh;
      int s = ws*32 + sl;
      float p = exp2f(qk[r] * SCL);
      *reinterpret_cast<__bf16*>(plds + q*512 + ((s*2) ^ ((q & 7) << 4))) = (__bf16)p;
    }
    WAITL();
    BAR();   // P(t-1) visible

    #pragma unroll
    for (int r = 0; r < 16; ++r) qk[r] = 0.f;

    const u8* kT = kptr + (size_t)t*524288;
    const u8* vT = vptr + (size_t)(t-1)*524288;
    bf16x8 aqA = ldA(0);
    bf16x8 pa0, pa1, pa2, pa3;

    #pragma unroll 1
    for (int ib = 0; ib < 7; ++ib) {
      #pragma unroll
      for (int j2 = 0; j2 < 8; ++j2) {
        const int j = ib*8 + j2;
        bf16x8 aqN = ldA(j + 1);
        if (j2 == 0) {
          pa0 = ldP(0, ib); pa1 = ldP(1, ib); pa2 = ldP(2, ib); pa3 = ldP(3, ib);
          if (qh == 0 && ws == ib) {
            lacc[0] = __builtin_amdgcn_mfma_f32_16x16x32_bf16(pa0, ones, lacc[0], 0, 0, 0);
            lacc[1] = __builtin_amdgcn_mfma_f32_16x16x32_bf16(pa1, ones, lacc[1], 0, 0, 0);
            lacc[2] = __builtin_amdgcn_mfma_f32_16x16x32_bf16(pa2, ones, lacc[2], 0, 0, 0);
            lacc[3] = __builtin_amdgcn_mfma_f32_16x16x32_bf16(pa3, ones, lacc[3], 0, 0, 0);
          }
        }
        const int nf = j2 >> 1;
        __builtin_amdgcn_s_setprio(1);
        qk = __builtin_amdgcn_mfma_f32_32x32x16_bf16(aqA, bk[j2 & 3], qk, 0, 0, 0);
        if ((j2 & 1) == 0) {
          Oacc[0][nf] = __builtin_amdgcn_mfma_f32_16x16x32_bf16(pa0, bv[nf], Oacc[0][nf], 0, 0, 0);
          Oacc[1][nf] = __builtin_amdgcn_mfma_f32_16x16x32_bf16(pa1, bv[nf], Oacc[1][nf], 0, 0, 0);
        } else {
          Oacc[2][nf] = __builtin_amdgcn_mfma_f32_16x16x32_bf16(pa2, bv[nf], Oacc[2][nf], 0, 0, 0);
          Oacc[3][nf] = __builtin_amdgcn_mfma_f32_16x16x32_bf16(pa3, bv[nf], Oacc[3][nf], 0, 0, 0);
        }
        __builtin_amdgcn_s_setprio(0);
        bk[j2 & 3] = ldU(kT, j + 4);
        if (j2 & 1) bv[nf] = ldU(vT, (ib + 1)*8 + voff + nf);
        aqA = aqN;
      }
    }
    #pragma unroll
    for (int j2 = 0; j2 < 8; ++j2) {                   // tail ib=7, j = 56..63
      const int j = 56 + j2;
      bf16x8 aqN = (j < 63) ? ldA(j + 1) : aqA;
      if (j2 == 0) {
        pa0 = ldP(0, 7); pa1 = ldP(1, 7); pa2 = ldP(2, 7); pa3 = ldP(3, 7);
        if (qh == 0 && ws == 7) {
          lacc[0] = __builtin_amdgcn_mfma_f32_16x16x32_bf16(pa0, ones, lacc[0], 0, 0, 0);
          lacc[1] = __builtin_amdgcn_mfma_f32_16x16x32_bf16(pa1, ones, lacc[1], 0, 0, 0);
          lacc[2] = __builtin_amdgcn_mfma_f32_16x16x32_bf16(pa2, ones, lacc[2], 0, 0, 0);
          lacc[3] = __builtin_amdgcn_mfma_f32_16x16x32_bf16(pa3, ones, lacc[3], 0, 0, 0);
        }
      }
      const int nf = j2 >> 1;
      __builtin_amdgcn_s_setprio(1);
      qk = __builtin_amdgcn_mfma_f32_32x32x16_bf16(aqA, bk[j2 & 3], qk, 0, 0, 0);
      if ((j2 & 1) == 0) {
        Oacc[0][nf] = __builtin_amdgcn_mfma_f32_16x16x32_bf16(pa0, bv[nf], Oacc[0][nf], 0, 0, 0);
        Oacc[1][nf] = __builtin_amdgcn_mfma_f32_16x16x32_bf16(pa1, bv[nf], Oacc[1][nf], 0, 0, 0);
      } else {
        Oacc[2][nf] = __builtin_amdgcn_mfma_f32_16x16x32_bf16(pa2, bv[nf], Oacc[2][nf], 0, 0, 0);
        Oacc[3][nf] = __builtin_amdgcn_mfma_f32_16x16x32_bf16(pa3, bv[nf], Oacc[3][nf], 0, 0, 0);
      }
      __builtin_amdgcn_s_setprio(0);
      if (j2 < 4) bk[j2] = ldU(kT, 60 + j2);
      else        bk[j2 - 4] = ldU(kT + 524288, j2 - 4);   // K(t+1)
      if (j2 & 1) bv[nf] = ldU(vT + 524288, voff + nf);    // V(t) ks=0
      aqA = aqN;
    }
  }

  // ================= epilogue: softmax(15) + PV-only =================
  BAR();
  #pragma unroll
  for (int r = 0; r < 16; ++r) {
    int q = qh*32 + (r & 3) + 8*(r >> 2) + 4*sh;
    int s = ws*32 + sl;
    float p = exp2f(qk[r] * SCL);
    *reinterpret_cast<__bf16*>(plds + q*512 + ((s*2) ^ ((q & 7) << 4))) = (__bf16)p;
  }
  WAITL();
  BAR();

  {
    const u8* vT = vptr + (size_t)(NT_-1)*524288;
    bf16x8 pa0, pa1, pa2, pa3;
    #pragma unroll 1
    for (int ib = 0; ib < 8; ++ib) {
      #pragma unroll
      for (int j2 = 0; j2 < 8; ++j2) {
        if (j2 == 0) {
          pa0 = ldP(0, ib); pa1 = ldP(1, ib); pa2 = ldP(2, ib); pa3 = ldP(3, ib);
          if (qh == 0 && ws == ib) {
            lacc[0] = __builtin_amdgcn_mfma_f32_16x16x32_bf16(pa0, ones, lacc[0], 0, 0, 0);
            lacc[1] = __builtin_amdgcn_mfma_f32_16x16x32_bf16(pa1, ones, lacc[1], 0, 0, 0);
            lacc[2] = __builtin_amdgcn_mfma_f32_16x16x32_bf16(pa2, ones, lacc[2], 0, 0, 0);
            lacc[3] = __builtin_amdgcn_mfma_f32_16x16x32_bf16(pa3, ones, lacc[3], 0, 0, 0);
          }
        }
        const int nf = j2 >> 1;
        __builtin_amdgcn_s_setprio(1);
        if ((j2 & 1) == 0) {
          Oacc[0][nf] = __builtin_amdgcn_mfma_f32_16x16x32_bf16(pa0, bv[nf], Oacc[0][nf], 0, 0, 0);
          Oacc[1][nf] = __builtin_amdgcn_mfma_f32_16x16x32_bf16(pa1, bv[nf], Oacc[1][nf], 0, 0, 0);
        } else {
          Oacc[2][nf] = __builtin_amdgcn_mfma_f32_16x16x32_bf16(pa2, bv[nf], Oacc[2][nf], 0, 0, 0);
          Oacc[3][nf] = __builtin_amdgcn_mfma_f32_16x16x32_bf16(pa3, bv[nf], Oacc[3][nf], 0, 0, 0);
        }
        __builtin_amdgcn_s_setprio(0);
        if ((j2 & 1) && ib < 7) bv[nf] = ldU(vT, (ib + 1)*8 + voff + nf);
      }
    }
  }
  BAR();   // all plds reads done

  // ================= l: combine 8 ks-partials, write O =================
  float* lred = (float*)plds;
  if (qh == 0 && lr == 0) {
    #pragma unroll
    for (int mq = 0; mq < 4; ++mq)
      #pragma unroll
      for (int j = 0; j < 4; ++j)
        lred[ws*64 + mq*16 + lg*4 + j] = lacc[mq][j];
  }
  WAITL();
  BAR();

  float* Ob = Og + ((size_t)b*LQ_ + (size_t)qt*BQ_)*DH_;
  #pragma unroll
  for (int mq = 0; mq < 4; ++mq)
    #pragma unroll
    for (int j = 0; j < 4; ++j) {
      int q = mq*16 + lg*4 + j;
      float s = 0.f;
      #pragma unroll
      for (int k = 0; k < 8; ++k) s += lred[k*64 + q];
      float rinv = 1.0f / s;
      #pragma unroll
      for (int nf = 0; nf < 4; ++nf)
        Ob[(size_t)q*DH_ + w*64 + nf*16 + lr] = Oacc[mq][nf][j] * rinv;
    }
}

// ---------------- correctness-only fallback (ws too small; never expected) ----------------
__global__ void attn_naive(const float* __restrict__ Q, const float* __restrict__ S,
                           float* __restrict__ O)
{
  const int row = blockIdx.x;
  const int b = row >> 12, q = row & 4095;
  const float* qp = Q + ((size_t)b*LQ_ + q)*DH_;
  const float* sp = S + (size_t)b*LS_*DH_;
  __shared__ float qs[DH_];
  __shared__ float osum[DH_];
  __shared__ float lsum;
  for (int i = threadIdx.x; i < DH_; i += 256) { qs[i] = qp[i]; osum[i] = 0.f; }
  if (threadIdx.x == 0) lsum = 0.f;
  __syncthreads();
  float lpart = 0.f;
  for (int s0 = threadIdx.x; s0 < LS_; s0 += 256) {
    const float* sr = sp + (size_t)s0*DH_;
    float dot = 0.f;
    for (int d = 0; d < DH_; ++d) dot += qs[d]*sr[d];
    float p = __expf(dot * 0.03125f);
    lpart += p;
    for (int d = 0; d < DH_; ++d) atomicAdd(&osum[d], p*sr[d]);
  }
  atomicAdd(&lsum, lpart);
  __syncthreads();
  float rinv = 1.0f / lsum;
  float* op = O + ((size_t)b*LQ_ + q)*DH_;
  for (int i = threadIdx.x; i < DH_; i += 256) op[i] = osum[i]*rinv;
}

extern "C" void kernel_launch(void* const* d_in, const int* in_sizes, int n_in,
                              void* d_out, int out_size, void* d_ws, size_t ws_size,
                              hipStream_t stream)
{
  const float* Q = (const float*)d_in[0];
  const float* S = (const float*)d_in[1];
  float* out = (float*)d_out;

  const size_t kf_bytes = (size_t)B_*NT_*8*64*1024;   // 32 MiB (bf16)
  const size_t vf_bytes = (size_t)B_*NT_*8*64*1024;   // 32 MiB (bf16)
  const size_t need = kf_bytes + vf_bytes;            // 64 MiB

  if (ws_size >= need) {
    u8* Kf = (u8*)d_ws;
    u8* Vf = Kf + kf_bytes;
    cvt_kernel<<<dim3(64, 16, 4), 256, 0, stream>>>(S, Kf, Vf);
    attn_kernel<<<dim3(256), NTH, 0, stream>>>(Q, Kf, Vf, out);
  } else {
    attn_naive<<<dim3(B_*LQ_), 256, 0, stream>>>(Q, S, out);
  }
}